// Round 2
// baseline (312.540 us; speedup 1.0000x reference)
//
#include <hip/hip_runtime.h>
#include <hip/hip_bf16.h>
#include <stdint.h>

// Problem: B=4, N=M=4096, C=1024, D=128. Inputs/outputs are FP32 (per
// reference dtypes); internal compute uses bf16 MFMA.
//   q = (x@Wq)/sqrt(D); k = y@Wk; v = y@Wv
//   a = softmax_fullrow(q k^T); a = triu(a, 1); out = a @ v
// out[n] = (sum_{m>n} e^{s} v[m]) / (sum_all e^{s})  -> online softmax,
// full-row denominator, masked numerator.

typedef __attribute__((ext_vector_type(8))) __bf16    bf16x8;
typedef __attribute__((ext_vector_type(4))) float     floatx4;
typedef __attribute__((ext_vector_type(8))) uint16_t  u16x8;

#define DEVFN __device__ __forceinline__

DEVFN uint16_t f32_to_bf16(float f) {                 // round-to-nearest-even
  uint32_t u = __builtin_bit_cast(uint32_t, f);
  u += 0x7FFFu + ((u >> 16) & 1u);
  return (uint16_t)(u >> 16);
}

// ---------------- Phase 0: W [1024,128] fp32 -> Wt [128,1024] bf16 (x3) ----
__global__ __launch_bounds__(256) void wt_kernel(
    const float* __restrict__ Wq, const float* __restrict__ Wk,
    const float* __restrict__ Wv, uint16_t* __restrict__ wt) {
  int tid = blockIdx.x * 256 + threadIdx.x;   // 3 * 16384 threads
  int mat = tid >> 14;
  int rem = tid & 16383;
  int n  = rem & 127;          // output row
  int k0 = rem >> 7;           // 0..127 -> k block of 8
  const float* W = (mat == 0) ? Wq : ((mat == 1) ? Wk : Wv);
  u16x8 v;
#pragma unroll
  for (int j = 0; j < 8; ++j) v[j] = f32_to_bf16(W[(k0 * 8 + j) * 128 + n]);
  *(u16x8*)&wt[mat * (128 * 1024) + n * 1024 + k0 * 8] = v;
}

// ---------------- Phase 1: fused QKV GEMM ----------------------------------
// grid (128 row-tiles, 3 mats), 256 thr. C-tile 128x128, BK=64.
// A (x or y) is fp32, converted to bf16 during staging. Wt already bf16.
// mat 2 (v) is stored transposed: vt[b][d][m].
__global__ __launch_bounds__(256) void qkv_kernel(
    const float* __restrict__ x, const float* __restrict__ y,
    const uint16_t* __restrict__ wt, uint16_t* __restrict__ q,
    uint16_t* __restrict__ k, uint16_t* __restrict__ vt) {
  constexpr int LDT = 72;  // 64 + 8 pad
  __shared__ __align__(16) uint16_t sA[128 * LDT];
  __shared__ __align__(16) uint16_t sW[128 * LDT];
  const int t = threadIdx.x;
  const int mat = blockIdx.y;
  const int rt = blockIdx.x;
  const float* A = (mat == 0) ? x : y;
  const uint16_t* Wt = wt + mat * (128 * 1024);
  const int lane = t & 63, wv = t >> 6;
  const int cidx = lane & 15, quad = lane >> 4;
  const int sr = t >> 3;          // staging: 32 rows per pass
  const int sc = (t & 7) * 8;     // 8 lanes x 8 elems = 64-wide
  const int Arow0 = rt * 128;

  floatx4 acc[2][8];
#pragma unroll
  for (int rg = 0; rg < 2; ++rg)
#pragma unroll
    for (int ng = 0; ng < 8; ++ng) acc[rg][ng] = (floatx4){0.f, 0.f, 0.f, 0.f};

  for (int kt = 0; kt < 16; ++kt) {
#pragma unroll
    for (int u = 0; u < 4; ++u) {
      int row = u * 32 + sr;
      const float* ap = &A[(size_t)(Arow0 + row) * 1024 + kt * 64 + sc];
      float4 a0 = *(const float4*)ap;
      float4 a1 = *(const float4*)(ap + 4);
      u16x8 av;
      av[0] = f32_to_bf16(a0.x); av[1] = f32_to_bf16(a0.y);
      av[2] = f32_to_bf16(a0.z); av[3] = f32_to_bf16(a0.w);
      av[4] = f32_to_bf16(a1.x); av[5] = f32_to_bf16(a1.y);
      av[6] = f32_to_bf16(a1.z); av[7] = f32_to_bf16(a1.w);
      *(u16x8*)&sA[row * LDT + sc] = av;
      *(u16x8*)&sW[row * LDT + sc] =
          *(const u16x8*)&Wt[row * 1024 + kt * 64 + sc];
    }
    __syncthreads();
    bf16x8 af[2][2];
#pragma unroll
    for (int rg = 0; rg < 2; ++rg)
#pragma unroll
      for (int ks = 0; ks < 2; ++ks)
        af[rg][ks] = *(const bf16x8*)
            &sA[(wv * 32 + rg * 16 + cidx) * LDT + ks * 32 + quad * 8];
#pragma unroll
    for (int ng = 0; ng < 8; ++ng) {
      bf16x8 b0 = *(const bf16x8*)&sW[(ng * 16 + cidx) * LDT + quad * 8];
      bf16x8 b1 = *(const bf16x8*)&sW[(ng * 16 + cidx) * LDT + 32 + quad * 8];
#pragma unroll
      for (int rg = 0; rg < 2; ++rg) {
        acc[rg][ng] = __builtin_amdgcn_mfma_f32_16x16x32_bf16(af[rg][0], b0, acc[rg][ng], 0, 0, 0);
        acc[rg][ng] = __builtin_amdgcn_mfma_f32_16x16x32_bf16(af[rg][1], b1, acc[rg][ng], 0, 0, 0);
      }
    }
    __syncthreads();
  }

  if (mat < 2) {
    const float scale = (mat == 0) ? 0.08838834764831845f : 1.0f; // 1/sqrt(128)
    uint16_t* outp = (mat == 0) ? q : k;
#pragma unroll
    for (int rg = 0; rg < 2; ++rg)
#pragma unroll
      for (int r = 0; r < 4; ++r) {
        int row = Arow0 + wv * 32 + rg * 16 + quad * 4 + r;
#pragma unroll
        for (int ng = 0; ng < 8; ++ng)
          outp[row * 128 + ng * 16 + cidx] = f32_to_bf16(acc[rg][ng][r] * scale);
      }
  } else {
    int bq = rt >> 5;                 // batch
    int mbase = (rt & 31) * 128;      // m within batch
#pragma unroll
    for (int rg = 0; rg < 2; ++rg)
#pragma unroll
      for (int r = 0; r < 4; ++r) {
        int m = mbase + wv * 32 + rg * 16 + quad * 4 + r;
#pragma unroll
        for (int ng = 0; ng < 8; ++ng)
          vt[(bq * 128 + ng * 16 + cidx) * 4096 + m] = f32_to_bf16(acc[rg][ng][r]);
      }
  }
}

// ---------------- Phase 2: flash attention, post-softmax triu mask ---------
// grid (64 q-tiles, 4 batches), 256 thr = 4 waves x 16 q-rows. KV chunk = 64.
__global__ __launch_bounds__(256) void attn_kernel(
    const uint16_t* __restrict__ q, const uint16_t* __restrict__ k,
    const uint16_t* __restrict__ vt, float* __restrict__ out) {
  constexpr int LDK = 136;  // 128 + 8 pad
  constexpr int LDV = 72;   // 64 + 8 pad
  constexpr int LDP = 72;
  __shared__ __align__(16) uint16_t sK[64 * LDK];
  __shared__ __align__(16) uint16_t sV[128 * LDV];
  __shared__ __align__(16) uint16_t sP[4 * 16 * LDP];
  const int t = threadIdx.x;
  const int lane = t & 63, wv = t >> 6;
  const int cidx = lane & 15, quad = lane >> 4;
  const int b = blockIdx.y;
  const int qt = blockIdx.x;
  const int qmin = qt * 64 + wv * 16;   // first q row of this wave (in batch)

  const uint16_t* qb = q + (b * 4096) * 128;
  const uint16_t* kb = k + (b * 4096) * 128;
  const uint16_t* vb = vt + (b * 128) * 4096;

  bf16x8 qf[4];   // Q A-fragments: row = lane&15, k = ks*32 + quad*8
#pragma unroll
  for (int ks = 0; ks < 4; ++ks)
    qf[ks] = *(const bf16x8*)&qb[(qmin + cidx) * 128 + ks * 32 + quad * 8];

  floatx4 O[8];
#pragma unroll
  for (int dg = 0; dg < 8; ++dg) O[dg] = (floatx4){0.f, 0.f, 0.f, 0.f};
  float mst[4], lst[4];
#pragma unroll
  for (int r = 0; r < 4; ++r) { mst[r] = -1e30f; lst[r] = 0.f; }

  const int krow = t >> 4, kcol = (t & 15) * 8;  // K stage: 16 rows/pass
  const int vrow = t >> 3, vcol = (t & 7) * 8;   // V stage: 32 d-rows/pass

  for (int it = 0; it < 64; ++it) {
    const int m0 = it * 64;
#pragma unroll
    for (int u = 0; u < 4; ++u) {
      int m = u * 16 + krow;
      *(u16x8*)&sK[m * LDK + kcol] = *(const u16x8*)&kb[(m0 + m) * 128 + kcol];
      int d = u * 32 + vrow;
      *(u16x8*)&sV[d * LDV + vcol] = *(const u16x8*)&vb[d * 4096 + m0 + vcol];
    }
    __syncthreads();

    // S = Q K^T (scale pre-folded into q). 16 MFMAs.
    floatx4 accS[4];
#pragma unroll
    for (int ng = 0; ng < 4; ++ng) accS[ng] = (floatx4){0.f, 0.f, 0.f, 0.f};
#pragma unroll
    for (int ks = 0; ks < 4; ++ks)
#pragma unroll
      for (int ng = 0; ng < 4; ++ng) {
        bf16x8 bk = *(const bf16x8*)&sK[(ng * 16 + cidx) * LDK + ks * 32 + quad * 8];
        accS[ng] = __builtin_amdgcn_mfma_f32_16x16x32_bf16(qf[ks], bk, accS[ng], 0, 0, 0);
      }

    // online softmax: C-layout row = quad*4+r, col = ng*16+cidx.
    float p[4][4], alpha[4];
#pragma unroll
    for (int r = 0; r < 4; ++r) {
      float mx = fmaxf(fmaxf(accS[0][r], accS[1][r]), fmaxf(accS[2][r], accS[3][r]));
#pragma unroll
      for (int s = 1; s < 16; s <<= 1) mx = fmaxf(mx, __shfl_xor(mx, s));
      float mnew = fmaxf(mst[r], mx);
      alpha[r] = exp2f((mst[r] - mnew) * 1.44269504f);
      float rs = 0.f;
#pragma unroll
      for (int ng = 0; ng < 4; ++ng) {
        p[ng][r] = exp2f((accS[ng][r] - mnew) * 1.44269504f);
        rs += p[ng][r];
      }
#pragma unroll
      for (int s = 1; s < 16; s <<= 1) rs += __shfl_xor(rs, s);
      lst[r] = alpha[r] * lst[r] + rs;   // denominator over ALL columns
      mst[r] = mnew;
    }
    if (__any(alpha[0] < 1.f || alpha[1] < 1.f || alpha[2] < 1.f || alpha[3] < 1.f)) {
#pragma unroll
      for (int dg = 0; dg < 8; ++dg)
#pragma unroll
        for (int r = 0; r < 4; ++r) O[dg][r] *= alpha[r];
    }

    // numerator: strict upper triangle only (col > row)
    bool allmask = (m0 + 63) <= qmin;        // every col <= every row
    if (!allmask) {
      if (m0 <= qmin + 15) {                 // straddles the diagonal
#pragma unroll
        for (int ng = 0; ng < 4; ++ng)
#pragma unroll
          for (int r = 0; r < 4; ++r) {
            int col = m0 + ng * 16 + cidx;
            int row = qmin + quad * 4 + r;
            if (col <= row) p[ng][r] = 0.f;
          }
      }
      // P: C-layout -> A-layout via wave-local LDS round trip
      uint16_t* pw = &sP[wv * 16 * LDP];
#pragma unroll
      for (int r = 0; r < 4; ++r)
#pragma unroll
        for (int ng = 0; ng < 4; ++ng)
          pw[(quad * 4 + r) * LDP + ng * 16 + cidx] = f32_to_bf16(p[ng][r]);
      asm volatile("s_waitcnt lgkmcnt(0)" ::: "memory");
      bf16x8 pa0 = *(const bf16x8*)&pw[cidx * LDP + quad * 8];
      bf16x8 pa1 = *(const bf16x8*)&pw[cidx * LDP + 32 + quad * 8];
#pragma unroll
      for (int dg = 0; dg < 8; ++dg) {
        bf16x8 v0 = *(const bf16x8*)&sV[(dg * 16 + cidx) * LDV + quad * 8];
        bf16x8 v1 = *(const bf16x8*)&sV[(dg * 16 + cidx) * LDV + 32 + quad * 8];
        O[dg] = __builtin_amdgcn_mfma_f32_16x16x32_bf16(pa0, v0, O[dg], 0, 0, 0);
        O[dg] = __builtin_amdgcn_mfma_f32_16x16x32_bf16(pa1, v1, O[dg], 0, 0, 0);
      }
    }
    __syncthreads();
  }

  float inv[4];
#pragma unroll
  for (int r = 0; r < 4; ++r) inv[r] = 1.0f / lst[r];  // lst > 0 always
#pragma unroll
  for (int r = 0; r < 4; ++r) {
    int n = qt * 64 + wv * 16 + quad * 4 + r;
#pragma unroll
    for (int dg = 0; dg < 8; ++dg)
      out[(b * 4096 + n) * 128 + dg * 16 + cidx] = O[dg][r] * inv[r];
  }
}

extern "C" void kernel_launch(void* const* d_in, const int* in_sizes, int n_in,
                              void* d_out, int out_size, void* d_ws, size_t ws_size,
                              hipStream_t stream) {
  const float* x  = (const float*)d_in[0];
  const float* y  = (const float*)d_in[1];
  const float* Wq = (const float*)d_in[2];
  const float* Wk = (const float*)d_in[3];
  const float* Wv = (const float*)d_in[4];
  uint16_t* ws = (uint16_t*)d_ws;
  uint16_t* wt = ws;                      // 3 * 128*1024 bf16
  uint16_t* q  = ws + 3 * 128 * 1024;     // 4*4096*128 bf16
  uint16_t* k  = q + 4 * 4096 * 128;
  uint16_t* vt = k + 4 * 4096 * 128;      // transposed: [b][d][m]
  float* o = (float*)d_out;

  hipLaunchKernelGGL(wt_kernel,   dim3(192),    dim3(256), 0, stream, Wq, Wk, Wv, wt);
  hipLaunchKernelGGL(qkv_kernel,  dim3(128, 3), dim3(256), 0, stream, x, y, wt, q, k, vt);
  hipLaunchKernelGGL(attn_kernel, dim3(64, 4),  dim3(256), 0, stream, q, k, vt, o);
}